// Round 12
// baseline (221.315 us; speedup 1.0000x reference)
//
#include <hip/hip_runtime.h>
#include <cmath>

typedef _Float16 f16x8 __attribute__((ext_vector_type(8)));
typedef _Float16 f16x4 __attribute__((ext_vector_type(4)));
typedef float    f32x16 __attribute__((ext_vector_type(16)));

constexpr int NBATCH = 32;
constexpr int NSEQ   = 4096;
constexpr int NCH    = 128;
constexpr int NEXP   = 64;
constexpr int NE2    = 128;
constexpr int DIN    = 2 * NSEQ;       // 8192
constexpr int ROWS   = NBATCH * NCH;   // 4096
constexpr int KCH    = 8;              // split-K chunks (1024 features each)
constexpr int KT     = 32;             // K-tiles per chunk (32 features each)
constexpr float LOSC = 2048.0f;
constexpr float INV_LOSC = 1.0f / 2048.0f;

// ws layout: partials 16 MiB @0 ; Whi 2 MiB @32Mi ; Wlo 2 MiB @34Mi
constexpr size_t WS_WHI = 32ull << 20;
constexpr size_t WS_WLO = 34ull << 20;

// [rows][32] f16 tile, rows 64B: XOR 16B-granule with (row>>1)&3 (G4).
// Verified correct end-to-end in R2/R3/R5 (absmax 0.0).
__device__ __forceinline__ int swz_f16(int row, int g) {
    return row * 32 + ((g ^ ((row >> 1) & 3)) << 3);
}

__device__ __forceinline__ void gload_lds16(const void* g, void* l) {
    __builtin_amdgcn_global_load_lds(
        (const __attribute__((address_space(1))) unsigned int*)g,
        (__attribute__((address_space(3))) unsigned int*)l, 16, 0, 0);
}

// ---------------------------------------------------------------------------
// Prep: split W into f16 hi/lo with the granule swizzle pre-baked (rule #21).
// ---------------------------------------------------------------------------
__global__ __launch_bounds__(256)
void wprep_kernel(const float* __restrict__ Wm, const float* __restrict__ Wn,
                  _Float16* __restrict__ Whi, _Float16* __restrict__ Wlo)
{
    const int idx = (blockIdx.x * 256 + threadIdx.x) * 4;  // f32 index, 1M total
    const int row = idx >> 13;
    const int f   = idx & 8191;
    const float* src = (row < NEXP) ? (Wm + (size_t)row * DIN + f)
                                    : (Wn + (size_t)(row - NEXP) * DIN + f);
    const float4 v = *(const float4*)src;
    const int g  = (f >> 3) & 3;
    const int fs = (f & ~0x18) | ((g ^ ((row >> 1) & 3)) << 3);
    float vv[4] = { v.x, v.y, v.z, v.w };
    f16x4 h, l;
#pragma unroll
    for (int j = 0; j < 4; ++j) {
        _Float16 hj = (_Float16)vv[j];
        h[j] = hj;
        l[j] = (_Float16)((vv[j] - (float)hj) * LOSC);
    }
    *(f16x4*)&Whi[(size_t)row * 8192 + fs] = h;
    *(f16x4*)&Wlo[(size_t)row * 8192 + fs] = l;
}

// ---------------------------------------------------------------------------
// GEMM: split-f16 MFMA. LOW-PRESSURE geometry: block-tile 64c x 128e x K=1024,
// 4 waves each 32c x 64e -> acc = 64 VGPR (was 128; R2-R5 likely spilled past
// the 256 cap and scratch traffic was the invariant ~70us binder).
// Counted-vmcnt pipeline, depth-2 x reg prefetch, LDS 48 KiB (2 bufs).
// acc1 = hi*hi ; acc2 = hi*lo + lo*hi ; out = acc1 + acc2/2048.
// ---------------------------------------------------------------------------
__global__ __launch_bounds__(256, 2)
void gemm_kernel(const float* __restrict__ x,
                 const _Float16* __restrict__ Whi,
                 const _Float16* __restrict__ Wlo,
                 float* __restrict__ partials)
{
    // XCD map: XCD (l&7) owns kc = l&7 for all 64 row-tiles -> its 1 MiB W
    // slice (hi+lo) stays L2-resident.
    const int l  = blockIdx.x;
    const int kc = l & 7;
    const int rt = l >> 3;           // row-tile: 64 rows
    const int b  = rt >> 1;
    const int ch = rt & 1;           // which 64-channel half

    const int tid  = threadIdx.x;
    const int lane = tid & 63;
    const int wave = tid >> 6;
    const int wm   = wave & 1;       // c-subtile (32 rows)
    const int wn   = wave >> 1;      // e-half (64 experts)

    // per buffer: Ah[64*32] Al[64*32] Bh[128*32] Bl[128*32] = 12288 f16 = 24KiB
    __shared__ _Float16 lds[2 * 12288];

    f32x16 acc1[2], acc2[2];
#pragma unroll
    for (int ni = 0; ni < 2; ++ni)
#pragma unroll
        for (int r = 0; r < 16; ++r) { acc1[ni][r] = 0.f; acc2[ni][r] = 0.f; }

    // x: ((b*4096 + s)*128 + c)*2 + t ; plane (b,s) = 256 contiguous f32.
    // This block: s in [kc*512, +512), c in [ch*64, +64).
    const float* xchunk = x + (size_t)b * (NSEQ * 256) + (size_t)kc * (512 * 256) + ch * 128;
    const int cl  = tid & 63;        // channel-local (A row)
    const int pg  = tid >> 6;        // plane-group = granule (8 k each)
    const int fb0 = kc * 1024;

    const int e_ld = lane >> 2;
    const int goff = (lane & 3) * 8;

    float2 xr[2][4];   // depth-2 x prefetch (statically indexed)

    auto load_x = [&](int t, float2 (&dst)[4]) {
#pragma unroll
        for (int i = 0; i < 4; ++i)
            dst[i] = *(const float2*)(xchunk + (size_t)(t * 16 + pg * 4 + i) * 256 + cl * 2);
    };
    auto write_x = [&](int buf, float2 (&src)[4]) {
        _Float16* Ah = lds + buf * 12288;
        _Float16* Al = Ah + 2048;
        f16x8 h, lo;
#pragma unroll
        for (int i = 0; i < 4; ++i) {
            float a0 = src[i].x, a1 = src[i].y;
            _Float16 h0 = (_Float16)a0, h1 = (_Float16)a1;
            h[2 * i] = h0; h[2 * i + 1] = h1;
            lo[2 * i]     = (_Float16)((a0 - (float)h0) * LOSC);
            lo[2 * i + 1] = (_Float16)((a1 - (float)h1) * LOSC);
        }
        const int off = swz_f16(cl, pg);
        *(f16x8*)&Ah[off] = h;
        *(f16x8*)&Al[off] = lo;
    };
    auto issue_W = [&](int t, int buf) {
        const int fb = fb0 + t * 32;
        _Float16* Bh = lds + buf * 12288 + 4096;
        _Float16* Bl = Bh + 4096;
#pragma unroll
        for (int q = 0; q < 2; ++q) {
            const int e0 = wave * 32 + q * 16;    // 16 e-rows per 1KiB segment
            gload_lds16(Whi + (size_t)(e0 + e_ld) * 8192 + fb + goff, Bh + e0 * 32);
            gload_lds16(Wlo + (size_t)(e0 + e_ld) * 8192 + fb + goff, Bl + e0 * 32);
        }
    };
    auto mfma_tile = [&](int buf) {
        const _Float16* Ah = lds + buf * 12288;
        const _Float16* Al = Ah + 2048;
        const _Float16* Bh = Ah + 4096;
        const _Float16* Bl = Ah + 8192;
#pragma unroll
        for (int kk = 0; kk < 2; ++kk) {
            const int gk = kk * 2 + (lane >> 5);
            const int oa = swz_f16(wm * 32 + (lane & 31), gk);
            f16x8 ah = *(const f16x8*)&Ah[oa];
            f16x8 al = *(const f16x8*)&Al[oa];
#pragma unroll
            for (int ni = 0; ni < 2; ++ni) {
                const int ob = swz_f16(wn * 64 + ni * 32 + (lane & 31), gk);
                f16x8 bh = *(const f16x8*)&Bh[ob];
                f16x8 bl = *(const f16x8*)&Bl[ob];
                acc1[ni] = __builtin_amdgcn_mfma_f32_32x32x16_f16(ah, bh, acc1[ni], 0, 0, 0);
                acc2[ni] = __builtin_amdgcn_mfma_f32_32x32x16_f16(ah, bl, acc2[ni], 0, 0, 0);
                acc2[ni] = __builtin_amdgcn_mfma_f32_32x32x16_f16(al, bh, acc2[ni], 0, 0, 0);
            }
        }
    };

    // ---- prologue (sched_barriers pin vmem FIFO order for the vmcnt math) --
    issue_W(0, 0);                                   // FIFO: W0(4)
    __builtin_amdgcn_sched_barrier(0);
    load_x(0, xr[0]);                                // + x0(4)
    load_x(1, xr[1]);                                // + x1(4)
    __builtin_amdgcn_sched_barrier(0);
    write_x(0, xr[0]);       // auto-wait retires W0+x0; x1 stays in flight
    asm volatile("s_waitcnt vmcnt(4) lgkmcnt(0)" ::: "memory");
    __builtin_amdgcn_s_barrier();
    __builtin_amdgcn_sched_barrier(0);

    // ---- steady loop: outstanding across barrier = {W(t+1):4, x(t+2):4} ----
#pragma unroll 2
    for (int t = 0; t < KT - 2; ++t) {
        const int cur = t & 1;
        issue_W(t + 1, cur ^ 1);
        __builtin_amdgcn_sched_barrier(0);           // keep W older than x in FIFO
        load_x(t + 2, xr[cur]);
        __builtin_amdgcn_sched_barrier(0);
        mfma_tile(cur);
        write_x(cur ^ 1, xr[cur ^ 1]);               // auto-wait: vmcnt(8)
        asm volatile("s_waitcnt vmcnt(4) lgkmcnt(0)" ::: "memory");  // W landed
        __builtin_amdgcn_s_barrier();
        __builtin_amdgcn_sched_barrier(0);
    }
    // t = KT-2 (even -> cur=0)
    issue_W(KT - 1, 1);
    __builtin_amdgcn_sched_barrier(0);
    mfma_tile(0);
    write_x(1, xr[1]);
    asm volatile("s_waitcnt vmcnt(0) lgkmcnt(0)" ::: "memory");
    __builtin_amdgcn_s_barrier();
    // t = KT-1
    mfma_tile(1);

    // ---- epilogue: C/D (m74/m101): col=lane&31, row=(r&3)+8*(r>>2)+4*(lane>>5)
    float* outp = partials + ((size_t)kc * ROWS + (size_t)b * NCH + ch * 64) * NE2;
#pragma unroll
    for (int ni = 0; ni < 2; ++ni)
#pragma unroll
        for (int r = 0; r < 16; ++r) {
            const int rloc = (r & 3) + 8 * (r >> 2) + 4 * (lane >> 5);
            const int crow = wm * 32 + rloc;
            const int e    = wn * 64 + ni * 32 + (lane & 31);
            outp[(size_t)crow * NE2 + e] = acc1[ni][r] + acc2[ni][r] * INV_LOSC;
        }
}

// ---------------------------------------------------------------------------
// Gate: reduce split-K partials, bias, softplus, exact kthvalue top-2 keep,
// masked softmax. Block = 2 rows x 128 experts.
// ---------------------------------------------------------------------------
__global__ __launch_bounds__(256)
void gate_kernel(const float* __restrict__ partials,
                 const float* __restrict__ bm,
                 const float* __restrict__ bn,
                 float* __restrict__ out)
{
    const int tid  = threadIdx.x;
    const int rl   = tid >> 7;
    const int e    = tid & 127;
    const int lane = tid & 63;
    const int row  = blockIdx.x * 2 + rl;

    const float* p = partials + (size_t)row * NE2 + e;
    float s = 0.f;
#pragma unroll
    for (int kc = 0; kc < KCH; ++kc)
        s += p[(size_t)kc * ROWS * NE2];

    __shared__ float spl[2][64];
    if (e >= NEXP) {
        float nz = s + bn[lane];
        spl[rl][lane] = fmaxf(nz, 0.f) + log1pf(expf(-fabsf(nz)));
    }
    __syncthreads();
    if (e < NEXP) {
        float g = s + bm[lane] + spl[rl][lane];

        float v  = g;
        float m1 = v;
#pragma unroll
        for (int o = 32; o > 0; o >>= 1) m1 = fmaxf(m1, __shfl_xor(m1, o));
        unsigned long long b1 = __ballot(v == m1);
        int l1 = __ffsll(b1) - 1;
        if (lane == l1) v = -INFINITY;
        float m2 = v;
#pragma unroll
        for (int o = 32; o > 0; o >>= 1) m2 = fmaxf(m2, __shfl_xor(m2, o));
        unsigned long long b2 = __ballot(v == m2);
        int l2 = __ffsll(b2) - 1;
        if (lane == l2) v = -INFINITY;
        float kth = v;
#pragma unroll
        for (int o = 32; o > 0; o >>= 1) kth = fmaxf(kth, __shfl_xor(kth, o));

        float ev  = (g > kth) ? expf(g - m1) : 0.f;
        float den = ev;
#pragma unroll
        for (int o = 32; o > 0; o >>= 1) den += __shfl_xor(den, o);
        out[(size_t)row * NEXP + lane] = ev / den;
    }
}

extern "C" void kernel_launch(void* const* d_in, const int* in_sizes, int n_in,
                              void* d_out, int out_size, void* d_ws, size_t ws_size,
                              hipStream_t stream)
{
    const float* x  = (const float*)d_in[0];
    const float* Wm = (const float*)d_in[1];
    const float* bm = (const float*)d_in[2];
    const float* Wn = (const float*)d_in[3];
    const float* bn = (const float*)d_in[4];
    float* out      = (float*)d_out;

    float*     partials = (float*)d_ws;                       // 16 MiB
    _Float16*  Whi      = (_Float16*)((char*)d_ws + WS_WHI);  // 2 MiB
    _Float16*  Wlo      = (_Float16*)((char*)d_ws + WS_WLO);  // 2 MiB

    wprep_kernel<<<1024, 256, 0, stream>>>(Wm, Wn, Whi, Wlo);
    gemm_kernel<<<512, 256, 0, stream>>>(x, Whi, Wlo, partials);
    gate_kernel<<<ROWS / 2, 256, 0, stream>>>(partials, bm, bn, out);
}